// Round 9
// baseline (239.149 us; speedup 1.0000x reference)
//
#include <hip/hip_runtime.h>
#include <hip/hip_bf16.h>

// GraphSAGE 2-layer forward — CSR-gather + bf16 MFMA GEMMs.
//   zl = x@W1l, zr = x@W1r      (bf16 MFMA, SPLIT packed arrays [n,64])
//   h  = sigmoid(mean(zl) + zr + b1)            (h bf16 [n,64])
//   out = [mean(h) | h] @ [W2l;W2r] + b2        (fused gather+cat-GEMM)
//
// R9 changes vs 186µs:
//  - Sort once, reuse: agg_h exports its sorted edge list (csr) + per-node
//    deg; agg_gemm2 fast path = coalesced csr load + 64-wide shfl prefix
//    (no TILE_SORT). Fallback to sort for tiles > ECAP (rare; ECAP=2048).
//  - scan merged into the scatter+gemm1 dispatch (5 -> 4): scan blocks run
//    in-grid; scatter blocks spin on scan_done (flags pre-zeroed by prep,
//    no poison hazard); gemm blocks independent -> scan hides under gemm1.
//  - TILE_SORT 64-bin prefix now wave-parallel (6 shfl_up steps, was serial).

#define N_FEAT 128
#define HID 64
#define NCLS 40
#define NE_BLK 4096
#define ECAP 2048

typedef short short8 __attribute__((ext_vector_type(8)));
typedef float floatx4 __attribute__((ext_vector_type(4)));

static __device__ __forceinline__ short f2bf(float x) {
    __hip_bfloat16 h = __float2bfloat16(x);
    return __builtin_bit_cast(short, h);
}
static __device__ __forceinline__ float bf2f(unsigned short u) {
    unsigned int v = ((unsigned int)u) << 16;
    return __builtin_bit_cast(float, v);
}

// accumulate up to 4 edges (clamped-index trick) of a 4-feat (uint2) column.
#define GATHER4(SRC, Zsrc, AC)                                               \
    for (int r = 0; r < d; r += 4) {                                         \
        int i1 = (r + 1 < d) ? r + 1 : d - 1;                                \
        int i2 = (r + 2 < d) ? r + 2 : d - 1;                                \
        int i3 = (r + 3 < d) ? r + 3 : d - 1;                                \
        int j0 = SRC[s + r], j1 = SRC[s + i1];                               \
        int j2 = SRC[s + i2], j3 = SRC[s + i3];                              \
        uint2 v0 = *(const uint2*)(Zsrc + (size_t)j0 * 64 + col * 4);        \
        uint2 v1 = *(const uint2*)(Zsrc + (size_t)j1 * 64 + col * 4);        \
        uint2 v2 = *(const uint2*)(Zsrc + (size_t)j2 * 64 + col * 4);        \
        uint2 v3 = *(const uint2*)(Zsrc + (size_t)j3 * 64 + col * 4);        \
        float w1 = (r + 1 < d) ? 1.f : 0.f;                                  \
        float w2 = (r + 2 < d) ? 1.f : 0.f;                                  \
        float w3 = (r + 3 < d) ? 1.f : 0.f;                                  \
        AC[0] += bf2f((unsigned short)(v0.x & 0xffffu));                     \
        AC[1] += bf2f((unsigned short)(v0.x >> 16));                         \
        AC[2] += bf2f((unsigned short)(v0.y & 0xffffu));                     \
        AC[3] += bf2f((unsigned short)(v0.y >> 16));                         \
        AC[0] = fmaf(w1, bf2f((unsigned short)(v1.x & 0xffffu)), AC[0]);     \
        AC[1] = fmaf(w1, bf2f((unsigned short)(v1.x >> 16)), AC[1]);         \
        AC[2] = fmaf(w1, bf2f((unsigned short)(v1.y & 0xffffu)), AC[2]);     \
        AC[3] = fmaf(w1, bf2f((unsigned short)(v1.y >> 16)), AC[3]);         \
        AC[0] = fmaf(w2, bf2f((unsigned short)(v2.x & 0xffffu)), AC[0]);     \
        AC[1] = fmaf(w2, bf2f((unsigned short)(v2.x >> 16)), AC[1]);         \
        AC[2] = fmaf(w2, bf2f((unsigned short)(v2.y & 0xffffu)), AC[2]);     \
        AC[3] = fmaf(w2, bf2f((unsigned short)(v2.y >> 16)), AC[3]);         \
        AC[0] = fmaf(w3, bf2f((unsigned short)(v3.x & 0xffffu)), AC[0]);     \
        AC[1] = fmaf(w3, bf2f((unsigned short)(v3.x >> 16)), AC[1]);         \
        AC[2] = fmaf(w3, bf2f((unsigned short)(v3.y & 0xffffu)), AC[2]);     \
        AC[3] = fmaf(w3, bf2f((unsigned short)(v3.y >> 16)), AC[3]);         \
    }

// per-chunk in-LDS counting sort of [E0+c0, E0+c0+cn) into elist (sorted by
// local dst). Wave-parallel 64-bin prefix. Leaves cnt[i]=deg_i, pos[i]=end_i.
#define TILE_SORT()                                                          \
    __syncthreads();                                                         \
    if (t < 64) cnt[t] = 0;                                                  \
    __syncthreads();                                                         \
    for (int j = t; j < cn; j += 256)                                        \
        atomicAdd(&cnt[ebuf[E0 + c0 + j] >> 26], 1);                         \
    __syncthreads();                                                         \
    if (t < 64) {                                                            \
        int v = cnt[t];                                                      \
        int xx = v;                                                          \
        _Pragma("unroll")                                                    \
        for (int o = 1; o < 64; o <<= 1) {                                   \
            int y = __shfl_up(xx, o);                                        \
            if (t >= o) xx += y;                                             \
        }                                                                    \
        pos[t] = xx - v; /* exclusive start = cursor */                      \
    }                                                                        \
    __syncthreads();                                                         \
    for (int j = t; j < cn; j += 256) {                                      \
        unsigned u = ebuf[E0 + c0 + j];                                      \
        int r = atomicAdd(&pos[u >> 26], 1);                                 \
        elist[r] = (int)(u & 0x03FFFFFFu);                                   \
    }                                                                        \
    __syncthreads();

// ---------------------------------------------------------------------------
// Weight prep (wt1 [128][128], wt2cat [48][128]) + 64-node-bucket histogram
// (LDS bins, key = dst>>6) + flag zero. One dispatch, 147 blocks.
// ---------------------------------------------------------------------------
__global__ void prep_hist(const float* __restrict__ W1l, const float* __restrict__ W1r,
                          const float* __restrict__ W2l, const float* __restrict__ W2r,
                          unsigned short* __restrict__ wt1,
                          unsigned short* __restrict__ wt2,
                          int* __restrict__ flags,
                          const int* __restrict__ ei, int ne, int n,
                          int* __restrict__ bh, int nbe) {
    __shared__ int bins[2048];
    const int b = blockIdx.x, t = threadIdx.x;
    const int nbuck = (n + 63) >> 6;
    for (int i = t; i < nbuck; i += 256) bins[i] = 0;
    __syncthreads();
    const int e0 = b * NE_BLK;
    const int lim = (e0 + NE_BLK < ne) ? (e0 + NE_BLK) : ne;
    for (int e = e0 + t; e < lim; e += 256)
        atomicAdd(&bins[ei[ne + e] >> 6], 1);

    int i = b * 256 + t;
    if (i < 128 * 128) {
        int nn = i >> 7, k = i & 127;
        float v = (nn < 64) ? W1l[k * 64 + nn] : W1r[k * 64 + (nn - 64)];
        wt1[nn * 128 + k] = (unsigned short)f2bf(v);
    } else if (i < 128 * 128 + 48 * 128) {
        int j = i - 128 * 128;
        int nn = j >> 7, k = j & 127;
        float v = 0.f;
        if (nn < 40)
            v = (k < 64) ? W2l[k * 40 + nn] : W2r[(k - 64) * 40 + nn];
        wt2[nn * 128 + k] = (unsigned short)f2bf(v);
    }
    if (i < 256) flags[i] = 0;

    __syncthreads();
    for (int j = t; j < nbuck; j += 256) bh[(size_t)j * nbe + b] = bins[j];
}

// ---------------------------------------------------------------------------
// Layer-1 GEMM body (smem-pointer form for the heterogeneous kernel).
// ---------------------------------------------------------------------------
static __device__ __forceinline__ void gemm1_body(
    short* __restrict__ smem, const float* __restrict__ x,
    const unsigned short* __restrict__ Wt, unsigned short* __restrict__ Zl,
    unsigned short* __restrict__ Zr, int n, int bid) {
    constexpr int K = 128, LDA = K + 8, M = 128, MT = 8, KS = 4, QROW = 16;
    short* At = smem;             // 64 x LDA
    short* Bt = smem + 64 * LDA;  // 128 x LDA
    const int t = threadIdx.x;
    const int nodeBase = bid * 64;

    for (int q = t; q < 64 * QROW; q += 256) {
        int row = q / QROW;
        int k0 = (q % QROW) * 8;
        int node = nodeBase + row;
        short8 s = {0, 0, 0, 0, 0, 0, 0, 0};
        if (node < n) {
            const float* A = x + (size_t)node * K + k0;
            float4 v0 = *(const float4*)A;
            float4 v1 = *(const float4*)(A + 4);
            s[0] = f2bf(v0.x); s[1] = f2bf(v0.y);
            s[2] = f2bf(v0.z); s[3] = f2bf(v0.w);
            s[4] = f2bf(v1.x); s[5] = f2bf(v1.y);
            s[6] = f2bf(v1.z); s[7] = f2bf(v1.w);
        }
        *(short8*)&At[row * LDA + k0] = s;
    }
    for (int q = t; q < M * QROW; q += 256) {
        int row = q / QROW;
        int k0 = (q % QROW) * 8;
        *(short8*)&Bt[row * LDA + k0] =
            *(const short8*)((const short*)Wt + (size_t)row * K + k0);
    }
    __syncthreads();

    const int wave = t >> 6;
    const int lane = t & 63;
    const int m0 = wave * 16;
    const int fl = lane & 15;
    const int quad = lane >> 4;

    floatx4 acc[MT];
#pragma unroll
    for (int nt = 0; nt < MT; ++nt) acc[nt] = (floatx4){0.f, 0.f, 0.f, 0.f};

#pragma unroll
    for (int ks = 0; ks < KS; ++ks) {
        const int kb = ks * 32 + quad * 8;
        short8 a = *(const short8*)&At[(m0 + fl) * LDA + kb];
#pragma unroll
        for (int nt = 0; nt < MT; ++nt) {
            short8 b = *(const short8*)&Bt[(nt * 16 + fl) * LDA + kb];
            acc[nt] = __builtin_amdgcn_mfma_f32_16x16x32_bf16(a, b, acc[nt], 0, 0, 0);
        }
    }

#pragma unroll
    for (int nt = 0; nt < MT; ++nt) {
        const int col = nt * 16 + fl;
#pragma unroll
        for (int r = 0; r < 4; ++r) {
            int node = nodeBase + m0 + quad * 4 + r;
            if (node < n) {
                unsigned short v = (unsigned short)f2bf(acc[nt][r]);
                if (col < HID)
                    Zl[(size_t)node * HID + col] = v;
                else
                    Zr[(size_t)node * HID + (col - HID)] = v;
            }
        }
    }
}

// ---------------------------------------------------------------------------
// Merged dispatch 2: blocks [0,nsb) = lookback scan; [nsb,nsb+nbe) = bucket
// scatter (waits for scan via flags[128]); rest = layer-1 GEMM (independent,
// runs immediately — scan hides under it).
// flags layout: [0..nsb) lookback flags, [128] scan_done, [129] arrival cnt.
// ---------------------------------------------------------------------------
__global__ __launch_bounds__(256) void scan_scatter_gemm1(
    const int* __restrict__ bh, int* __restrict__ sbase, int tot, int nsb,
    int* __restrict__ bsums, int* __restrict__ flags,
    const int* __restrict__ ei, int ne, int n, unsigned* __restrict__ ebuf,
    int nbe, const float* __restrict__ x,
    const unsigned short* __restrict__ wt1, unsigned short* __restrict__ zl,
    unsigned short* __restrict__ zr) {
    __shared__ __align__(16) short smem[(64 + 128) * 136];
    const int b = blockIdx.x;
    const int t = threadIdx.x;
    if (b < nsb) {
        // ---- lookback exclusive scan: sbase[0]=0, sbase[i]=sum(bh[0..i-1])
        int* lds = (int*)smem;
        int* look = lds + 256;
        int* sprefix = look + 128;
        const int base = b * 2048 + t * 8;
        int v[8], s = 0;
#pragma unroll
        for (int i = 0; i < 8; ++i) {
            int idx = base + i;
            v[i] = (idx < tot) ? bh[idx] : 0;
            s += v[i];
        }
        lds[t] = s;
        __syncthreads();
        for (int o = 1; o < 256; o <<= 1) {
            int y = (t >= o) ? lds[t - o] : 0;
            __syncthreads();
            lds[t] += y;
            __syncthreads();
        }
        if (t == 255) {
            __hip_atomic_store(&bsums[b], lds[255], __ATOMIC_RELEASE,
                               __HIP_MEMORY_SCOPE_AGENT);
            __hip_atomic_store(&flags[b], 1, __ATOMIC_RELEASE,
                               __HIP_MEMORY_SCOPE_AGENT);
        }
        if (t < 128) look[t] = 0;
        __syncthreads();
        if (t < b) {
            while (__hip_atomic_load(&flags[t], __ATOMIC_ACQUIRE,
                                     __HIP_MEMORY_SCOPE_AGENT) == 0) {}
            look[t] = __hip_atomic_load(&bsums[t], __ATOMIC_RELAXED,
                                        __HIP_MEMORY_SCOPE_AGENT);
        }
        __syncthreads();
        if (t == 0) {
            int p = 0;
            for (int i = 0; i < b; ++i) p += look[i];
            sprefix[0] = p;
        }
        __syncthreads();
        int run = ((t == 0) ? 0 : lds[t - 1]) + sprefix[0];
#pragma unroll
        for (int i = 0; i < 8; ++i) {
            run += v[i];
            int idx = base + i;
            if (idx < tot) sbase[idx + 1] = run;
        }
        if (b == 0 && t == 0) sbase[0] = 0;
        // ---- completion: all writes fenced, last block sets scan_done
        __threadfence();
        __syncthreads();
        if (t == 0) {
            int arrived = __hip_atomic_fetch_add(&flags[129], 1,
                                                 __ATOMIC_ACQ_REL,
                                                 __HIP_MEMORY_SCOPE_AGENT);
            if (arrived == nsb - 1)
                __hip_atomic_store(&flags[128], 1, __ATOMIC_RELEASE,
                                   __HIP_MEMORY_SCOPE_AGENT);
        }
    } else if (b < nsb + nbe) {
        // ---- bucket scatter (waits for scan_done)
        if (t == 0) {
            while (__hip_atomic_load(&flags[128], __ATOMIC_ACQUIRE,
                                     __HIP_MEMORY_SCOPE_AGENT) == 0) {}
        }
        __syncthreads();
        (void)__hip_atomic_load(&flags[128], __ATOMIC_ACQUIRE,
                                __HIP_MEMORY_SCOPE_AGENT);
        int* bins = (int*)smem;
        const int sb = b - nsb;
        const int nbuck = (n + 63) >> 6;
        for (int i = t; i < nbuck; i += 256) bins[i] = 0;
        __syncthreads();
        const int e0 = sb * NE_BLK;
        const int lim = (e0 + NE_BLK < ne) ? (e0 + NE_BLK) : ne;
        for (int e = e0 + t; e < lim; e += 256) {
            int d = ei[ne + e];
            int s = ei[e];
            int bk = d >> 6;
            int r = atomicAdd(&bins[bk], 1);
            int p = sbase[(size_t)bk * nbe + sb] + r;
            ebuf[p] = ((unsigned)(d & 63) << 26) | (unsigned)s;
        }
    } else {
        gemm1_body(smem, x, wt1, zl, zr, n, b - nsb - nbe);
    }
}

// ---------------------------------------------------------------------------
// Layer-1 aggregate, 64-node tile per block. In-LDS counting sort, then
// quarter-wave gather. Exports sorted edge list (csrO) + per-node degree
// (degO) for reuse by agg_gemm2. h = sigmoid(mean(Zl)+Zr+bias), bf16 out.
// ---------------------------------------------------------------------------
__global__ __launch_bounds__(256) void agg_h(
    const unsigned short* __restrict__ Zl, const unsigned short* __restrict__ Zr,
    const unsigned* __restrict__ ebuf, const int* __restrict__ sbase, int nbe,
    const float* __restrict__ bias, unsigned short* __restrict__ hout,
    int* __restrict__ csrO, int* __restrict__ degO, int n) {
    __shared__ int elist[ECAP];
    __shared__ int cnt[64];
    __shared__ int pos[64];
    const int t = threadIdx.x;
    const int tile = blockIdx.x;
    const int base = tile * 64;
    const int E0 = sbase[(size_t)tile * nbe];
    const int E1 = sbase[(size_t)(tile + 1) * nbe];
    const int nedge = E1 - E0;

    const int lane = t & 63, wave = t >> 6;
    const int sub = lane >> 4, col = lane & 15;

    float a[4][4];
    int totd[4];
#pragma unroll
    for (int p = 0; p < 4; ++p) {
        totd[p] = 0;
#pragma unroll
        for (int j = 0; j < 4; ++j) a[p][j] = 0.f;
    }

    for (int c0 = 0; c0 < nedge; c0 += ECAP) {
        const int cn = (nedge - c0 < ECAP) ? (nedge - c0) : ECAP;
        TILE_SORT()
        // export sorted srcs for reuse by agg_gemm2
        for (int j = t; j < cn; j += 256) csrO[E0 + c0 + j] = elist[j];
#pragma unroll
        for (int p = 0; p < 4; ++p) {
            const int i = wave * 16 + p * 4 + sub;
            const int s = pos[i] - cnt[i];
            const int d = cnt[i];
            totd[p] += d;
            float* AC = a[p];
            GATHER4(elist, Zl, AC)
        }
    }

#pragma unroll
    for (int p = 0; p < 4; ++p) {
        const int i = wave * 16 + p * 4 + sub;
        const int node = base + i;
        if (node < n) {
            if (col == 0) degO[node] = totd[p];
            float inv = 1.0f / fmaxf((float)totd[p], 1.0f);
            uint2 z = *(const uint2*)(Zr + (size_t)node * 64 + col * 4);
            float4 bb = ((const float4*)bias)[col];
            float r0 = a[p][0] * inv + bf2f((unsigned short)(z.x & 0xffffu)) + bb.x;
            float r1 = a[p][1] * inv + bf2f((unsigned short)(z.x >> 16)) + bb.y;
            float r2 = a[p][2] * inv + bf2f((unsigned short)(z.y & 0xffffu)) + bb.z;
            float r3 = a[p][3] * inv + bf2f((unsigned short)(z.y >> 16)) + bb.w;
            r0 = 1.0f / (1.0f + __expf(-r0));
            r1 = 1.0f / (1.0f + __expf(-r1));
            r2 = 1.0f / (1.0f + __expf(-r2));
            r3 = 1.0f / (1.0f + __expf(-r3));
            uint2 pk;
            pk.x = (unsigned)(unsigned short)f2bf(r0) |
                   ((unsigned)(unsigned short)f2bf(r1) << 16);
            pk.y = (unsigned)(unsigned short)f2bf(r2) |
                   ((unsigned)(unsigned short)f2bf(r3) << 16);
            *(uint2*)(hout + (size_t)node * 64 + col * 4) = pk;
        }
    }
}

// ---------------------------------------------------------------------------
// Fused layer-2: fast path reuses agg_h's sorted list (coalesced csr load +
// 64-wide shfl prefix of deg — no sort); fallback sorts for tiles > ECAP.
// gather-mean(h) -> bf16 A-tile left half; h right half; K=128 cat-GEMM.
// ---------------------------------------------------------------------------
__global__ __launch_bounds__(256) void agg_gemm2(
    const unsigned short* __restrict__ h, const unsigned short* __restrict__ Wt,
    const float* __restrict__ bias, const unsigned* __restrict__ ebuf,
    const int* __restrict__ sbase, int nbe, const int* __restrict__ csrI,
    const int* __restrict__ degI, float* __restrict__ out, int n) {
    constexpr int LDA = 136;
    __shared__ __align__(16) short At[64 * LDA];
    __shared__ __align__(16) short Bt[48 * LDA];
    __shared__ int elist[ECAP];
    __shared__ int cnt[64];
    __shared__ int pos[64];
    const int t = threadIdx.x;
    const int tile = blockIdx.x;
    const int base = tile * 64;
    const int E0 = sbase[(size_t)tile * nbe];
    const int E1 = sbase[(size_t)(tile + 1) * nbe];
    const int nedge = E1 - E0;

    // stage h rows into At[:, 64:128)
    for (int q = t; q < 64 * 8; q += 256) {
        int row = q >> 3, k0 = (q & 7) * 8;
        int node = base + row;
        short8 s = {0, 0, 0, 0, 0, 0, 0, 0};
        if (node < n) s = *(const short8*)(h + (size_t)node * 64 + k0);
        *(short8*)&At[row * LDA + 64 + k0] = s;
    }
    // stage Bt (48 x 128)
    for (int q = t; q < 48 * 16; q += 256) {
        int row = q >> 4, k0 = (q & 15) * 8;
        *(short8*)&Bt[row * LDA + k0] =
            *(const short8*)((const short*)Wt + (size_t)row * 128 + k0);
    }

    const int lane = t & 63, wave = t >> 6;
    const int sub = lane >> 4, col = lane & 15;

    float a[4][4];
    int totd[4];
#pragma unroll
    for (int p = 0; p < 4; ++p) {
        totd[p] = 0;
#pragma unroll
        for (int j = 0; j < 4; ++j) a[p][j] = 0.f;
    }

    if (nedge <= ECAP) {
        // fast path: reuse sorted list from agg_h
        for (int j = t; j < nedge; j += 256) elist[j] = csrI[E0 + j];
        if (t < 64) {
            int node = base + t;
            int v = (node < n) ? degI[node] : 0;
            cnt[t] = v;
            int xx = v;
#pragma unroll
            for (int o = 1; o < 64; o <<= 1) {
                int y = __shfl_up(xx, o);
                if (t >= o) xx += y;
            }
            pos[t] = xx;  // inclusive end
        }
        __syncthreads();
#pragma unroll
        for (int p = 0; p < 4; ++p) {
            const int i = wave * 16 + p * 4 + sub;
            const int s = pos[i] - cnt[i];
            const int d = cnt[i];
            totd[p] = d;
            float* AC = a[p];
            GATHER4(elist, h, AC)
        }
    } else {
        // fallback: sort in-tile (chunked)
        for (int c0 = 0; c0 < nedge; c0 += ECAP) {
            const int cn = (nedge - c0 < ECAP) ? (nedge - c0) : ECAP;
            TILE_SORT()
#pragma unroll
            for (int p = 0; p < 4; ++p) {
                const int i = wave * 16 + p * 4 + sub;
                const int s = pos[i] - cnt[i];
                const int d = cnt[i];
                totd[p] += d;
                float* AC = a[p];
                GATHER4(elist, h, AC)
            }
        }
    }

    // gather epilogue -> At left half (bf16 mean; zero rows for node>=n)
#pragma unroll
    for (int p = 0; p < 4; ++p) {
        const int i = wave * 16 + p * 4 + sub;
        float inv = 1.0f / fmaxf((float)totd[p], 1.0f);
        uint2 pk;
        pk.x = (unsigned)(unsigned short)f2bf(a[p][0] * inv) |
               ((unsigned)(unsigned short)f2bf(a[p][1] * inv) << 16);
        pk.y = (unsigned)(unsigned short)f2bf(a[p][2] * inv) |
               ((unsigned)(unsigned short)f2bf(a[p][3] * inv) << 16);
        *(uint2*)&At[i * LDA + col * 4] = pk;
    }
    __syncthreads();

    // MFMA: K=128, 3 col-tiles (48 cols, 40 valid)
    const int m0 = wave * 16;
    const int fl = lane & 15;
    const int quad = lane >> 4;
    floatx4 acc[3];
#pragma unroll
    for (int nt = 0; nt < 3; ++nt) acc[nt] = (floatx4){0.f, 0.f, 0.f, 0.f};
#pragma unroll
    for (int ks = 0; ks < 4; ++ks) {
        const int kb = ks * 32 + quad * 8;
        short8 av = *(const short8*)&At[(m0 + fl) * LDA + kb];
#pragma unroll
        for (int nt = 0; nt < 3; ++nt) {
            short8 bv = *(const short8*)&Bt[(nt * 16 + fl) * LDA + kb];
            acc[nt] = __builtin_amdgcn_mfma_f32_16x16x32_bf16(av, bv, acc[nt], 0, 0, 0);
        }
    }
#pragma unroll
    for (int nt = 0; nt < 3; ++nt) {
        const int col2 = nt * 16 + fl;
        if (col2 < NCLS) {
            float bv = bias[col2];
#pragma unroll
            for (int r = 0; r < 4; ++r) {
                int node = base + m0 + quad * 4 + r;
                if (node < n)
                    out[(size_t)node * NCLS + col2] = acc[nt][r] + bv;
            }
        }
    }
}

// ---------------------------------------------------------------------------
extern "C" void kernel_launch(void* const* d_in, const int* in_sizes, int n_in,
                              void* d_out, int out_size, void* d_ws,
                              size_t ws_size, hipStream_t stream) {
    const float* x = (const float*)d_in[0];
    const int* ei = (const int*)d_in[1];
    const float* W1l = (const float*)d_in[2];
    const float* b1 = (const float*)d_in[3];
    const float* W1r = (const float*)d_in[4];
    const float* W2l = (const float*)d_in[5];
    const float* b2 = (const float*)d_in[6];
    const float* W2r = (const float*)d_in[7];
    float* out = (float*)d_out;

    const int n = in_sizes[0] / N_FEAT;  // 100000
    const int ne = in_sizes[1] / 2;      // 600000

    const int nbe = (ne + NE_BLK - 1) / NE_BLK;   // 147 edge blocks
    const int nbuck = (n + 63) >> 6;              // 1563 tiles
    const int tot = nbuck * nbe;                  // ~230K

    // ws layout
    unsigned short* zl1 = (unsigned short*)d_ws;
    unsigned short* zr1 = zl1 + (size_t)n * HID;
    unsigned short* h = zr1 + (size_t)n * HID;
    unsigned short* wt1 = h + (size_t)n * HID;
    unsigned short* wt2 = wt1 + 128 * 128;
    unsigned* ebuf = (unsigned*)(wt2 + 48 * 128);
    int* csr = (int*)(ebuf + ne);
    int* deg = csr + ne;
    int* bh = deg + n;
    int* sbase = bh + tot;
    int* bsums = sbase + (tot + 1);
    int* flags = bsums + 256;

    const int gblocks = (n + 63) / 64;            // 1563
    const int nsb = (tot + 2047) / 2048;          // 113 scan blocks

    // 1) weight prep + 64-node-bucket histogram + flag zero
    prep_hist<<<nbe, 256, 0, stream>>>(W1l, W1r, W2l, W2r, wt1, wt2, flags,
                                       ei, ne, n, bh, nbe);
    // 2) scan + bucket scatter + layer-1 GEMM (merged; scan hides under GEMM)
    scan_scatter_gemm1<<<nsb + nbe + gblocks, 256, 0, stream>>>(
        bh, sbase, tot, nsb, bsums, flags, ei, ne, n, ebuf, nbe, x, wt1, zl1,
        zr1);
    // 3) layer-1 aggregate -> h (+ export sorted csr/deg)
    agg_h<<<gblocks, 256, 0, stream>>>(zl1, zr1, ebuf, sbase, nbe, b1, h, csr,
                                       deg, n);
    // 4) fused layer-2 gather + cat-GEMM -> out (reuses sorted csr/deg)
    agg_gemm2<<<gblocks, 256, 0, stream>>>(h, wt2, b2, ebuf, sbase, nbe, csr,
                                           deg, out, n);
}

// Round 10
// 185.495 us; speedup vs baseline: 1.2892x; 1.2892x over previous
//
#include <hip/hip_runtime.h>
#include <hip/hip_bf16.h>

// GraphSAGE 2-layer forward — CSR-gather + bf16 MFMA GEMMs.
//   zl = x@W1l, zr = x@W1r      (bf16 MFMA, SPLIT packed arrays [n,64])
//   h  = sigmoid(mean(zl) + zr + b1)            (h bf16 [n,64])
//   out = [mean(h) | h] @ [W2l;W2r] + b2        (fused gather+cat-GEMM)
//
// R10 = R8 dispatch structure + R9's good parts:
//  - REVERTED R9's scan/scatter/gemm merge (cross-block spin-wait at agent
//    scope = coherence-probe storm: 105µs with VALUBusy 3.5%). scan_fused is
//    its own dispatch again (intra-dispatch lookback is fine: publish-first).
//  - KEPT sort-once/reuse: agg_h exports sorted csr + deg; agg_gemm2 fast
//    path loads them coalesced + 64-wide shfl prefix (no re-sort).
//  - KEPT wave-parallel 64-bin prefix in TILE_SORT.
//  - 5 dispatches: prep_hist, scan_fused, scatter+gemm1, agg_h, agg_gemm2.

#define N_FEAT 128
#define HID 64
#define NCLS 40
#define NE_BLK 4096
#define ECAP 2048

typedef short short8 __attribute__((ext_vector_type(8)));
typedef float floatx4 __attribute__((ext_vector_type(4)));

static __device__ __forceinline__ short f2bf(float x) {
    __hip_bfloat16 h = __float2bfloat16(x);
    return __builtin_bit_cast(short, h);
}
static __device__ __forceinline__ float bf2f(unsigned short u) {
    unsigned int v = ((unsigned int)u) << 16;
    return __builtin_bit_cast(float, v);
}

// accumulate up to 4 edges (clamped-index trick) of a 4-feat (uint2) column.
#define GATHER4(SRC, Zsrc, AC)                                               \
    for (int r = 0; r < d; r += 4) {                                         \
        int i1 = (r + 1 < d) ? r + 1 : d - 1;                                \
        int i2 = (r + 2 < d) ? r + 2 : d - 1;                                \
        int i3 = (r + 3 < d) ? r + 3 : d - 1;                                \
        int j0 = SRC[s + r], j1 = SRC[s + i1];                               \
        int j2 = SRC[s + i2], j3 = SRC[s + i3];                              \
        uint2 v0 = *(const uint2*)(Zsrc + (size_t)j0 * 64 + col * 4);        \
        uint2 v1 = *(const uint2*)(Zsrc + (size_t)j1 * 64 + col * 4);        \
        uint2 v2 = *(const uint2*)(Zsrc + (size_t)j2 * 64 + col * 4);        \
        uint2 v3 = *(const uint2*)(Zsrc + (size_t)j3 * 64 + col * 4);        \
        float w1 = (r + 1 < d) ? 1.f : 0.f;                                  \
        float w2 = (r + 2 < d) ? 1.f : 0.f;                                  \
        float w3 = (r + 3 < d) ? 1.f : 0.f;                                  \
        AC[0] += bf2f((unsigned short)(v0.x & 0xffffu));                     \
        AC[1] += bf2f((unsigned short)(v0.x >> 16));                         \
        AC[2] += bf2f((unsigned short)(v0.y & 0xffffu));                     \
        AC[3] += bf2f((unsigned short)(v0.y >> 16));                         \
        AC[0] = fmaf(w1, bf2f((unsigned short)(v1.x & 0xffffu)), AC[0]);     \
        AC[1] = fmaf(w1, bf2f((unsigned short)(v1.x >> 16)), AC[1]);         \
        AC[2] = fmaf(w1, bf2f((unsigned short)(v1.y & 0xffffu)), AC[2]);     \
        AC[3] = fmaf(w1, bf2f((unsigned short)(v1.y >> 16)), AC[3]);         \
        AC[0] = fmaf(w2, bf2f((unsigned short)(v2.x & 0xffffu)), AC[0]);     \
        AC[1] = fmaf(w2, bf2f((unsigned short)(v2.x >> 16)), AC[1]);         \
        AC[2] = fmaf(w2, bf2f((unsigned short)(v2.y & 0xffffu)), AC[2]);     \
        AC[3] = fmaf(w2, bf2f((unsigned short)(v2.y >> 16)), AC[3]);         \
        AC[0] = fmaf(w3, bf2f((unsigned short)(v3.x & 0xffffu)), AC[0]);     \
        AC[1] = fmaf(w3, bf2f((unsigned short)(v3.x >> 16)), AC[1]);         \
        AC[2] = fmaf(w3, bf2f((unsigned short)(v3.y & 0xffffu)), AC[2]);     \
        AC[3] = fmaf(w3, bf2f((unsigned short)(v3.y >> 16)), AC[3]);         \
    }

// per-chunk in-LDS counting sort of [E0+c0, E0+c0+cn) into elist (sorted by
// local dst). Wave-parallel 64-bin prefix. Leaves cnt[i]=deg_i, pos[i]=end_i.
#define TILE_SORT()                                                          \
    __syncthreads();                                                         \
    if (t < 64) cnt[t] = 0;                                                  \
    __syncthreads();                                                         \
    for (int j = t; j < cn; j += 256)                                        \
        atomicAdd(&cnt[ebuf[E0 + c0 + j] >> 26], 1);                         \
    __syncthreads();                                                         \
    if (t < 64) {                                                            \
        int v = cnt[t];                                                      \
        int xx = v;                                                          \
        _Pragma("unroll")                                                    \
        for (int o = 1; o < 64; o <<= 1) {                                   \
            int y = __shfl_up(xx, o);                                        \
            if (t >= o) xx += y;                                             \
        }                                                                    \
        pos[t] = xx - v; /* exclusive start = cursor */                      \
    }                                                                        \
    __syncthreads();                                                         \
    for (int j = t; j < cn; j += 256) {                                      \
        unsigned u = ebuf[E0 + c0 + j];                                      \
        int r = atomicAdd(&pos[u >> 26], 1);                                 \
        elist[r] = (int)(u & 0x03FFFFFFu);                                   \
    }                                                                        \
    __syncthreads();

// ---------------------------------------------------------------------------
// Weight prep (wt1 [128][128], wt2cat [48][128]) + 64-node-bucket histogram
// (LDS bins, key = dst>>6) + flag zero. One dispatch, 147 blocks.
// ---------------------------------------------------------------------------
__global__ void prep_hist(const float* __restrict__ W1l, const float* __restrict__ W1r,
                          const float* __restrict__ W2l, const float* __restrict__ W2r,
                          unsigned short* __restrict__ wt1,
                          unsigned short* __restrict__ wt2,
                          int* __restrict__ flags,
                          const int* __restrict__ ei, int ne, int n,
                          int* __restrict__ bh, int nbe) {
    __shared__ int bins[2048];
    const int b = blockIdx.x, t = threadIdx.x;
    const int nbuck = (n + 63) >> 6;
    for (int i = t; i < nbuck; i += 256) bins[i] = 0;
    __syncthreads();
    const int e0 = b * NE_BLK;
    const int lim = (e0 + NE_BLK < ne) ? (e0 + NE_BLK) : ne;
    for (int e = e0 + t; e < lim; e += 256)
        atomicAdd(&bins[ei[ne + e] >> 6], 1);

    int i = b * 256 + t;
    if (i < 128 * 128) {
        int nn = i >> 7, k = i & 127;
        float v = (nn < 64) ? W1l[k * 64 + nn] : W1r[k * 64 + (nn - 64)];
        wt1[nn * 128 + k] = (unsigned short)f2bf(v);
    } else if (i < 128 * 128 + 48 * 128) {
        int j = i - 128 * 128;
        int nn = j >> 7, k = j & 127;
        float v = 0.f;
        if (nn < 40)
            v = (k < 64) ? W2l[k * 40 + nn] : W2r[(k - 64) * 40 + nn];
        wt2[nn * 128 + k] = (unsigned short)f2bf(v);
    }
    if (i < 256) flags[i] = 0;

    __syncthreads();
    for (int j = t; j < nbuck; j += 256) bh[(size_t)j * nbe + b] = bins[j];
}

// ---------------------------------------------------------------------------
// Lookback exclusive scan (own dispatch; publish-first, deadlock-free):
// pre[0]=0, pre[i]=sum(in[0..i-1]); m ~230K.
// ---------------------------------------------------------------------------
__global__ void scan_fused(const int* __restrict__ in, int* __restrict__ pre,
                           int m, int* __restrict__ bsums,
                           int* __restrict__ flags) {
    __shared__ int lds[256];
    __shared__ int look[128];
    __shared__ int sprefix;
    const int b = blockIdx.x, t = threadIdx.x;
    const int base = b * 2048 + t * 8;
    int v[8], s = 0;
#pragma unroll
    for (int i = 0; i < 8; ++i) {
        int idx = base + i;
        v[i] = (idx < m) ? in[idx] : 0;
        s += v[i];
    }
    lds[t] = s;
    __syncthreads();
    for (int o = 1; o < 256; o <<= 1) {
        int y = (t >= o) ? lds[t - o] : 0;
        __syncthreads();
        lds[t] += y;
        __syncthreads();
    }
    if (t == 255) {
        __hip_atomic_store(&bsums[b], lds[255], __ATOMIC_RELEASE,
                           __HIP_MEMORY_SCOPE_AGENT);
        __hip_atomic_store(&flags[b], 1, __ATOMIC_RELEASE,
                           __HIP_MEMORY_SCOPE_AGENT);
    }
    if (t < 128) look[t] = 0;
    __syncthreads();
    if (t < b) {
        while (__hip_atomic_load(&flags[t], __ATOMIC_ACQUIRE,
                                 __HIP_MEMORY_SCOPE_AGENT) == 0) {}
        look[t] = __hip_atomic_load(&bsums[t], __ATOMIC_RELAXED,
                                    __HIP_MEMORY_SCOPE_AGENT);
    }
    __syncthreads();
    if (t == 0) {
        int p = 0;
        for (int i = 0; i < b; ++i) p += look[i];
        sprefix = p;
    }
    __syncthreads();
    int run = ((t == 0) ? 0 : lds[t - 1]) + sprefix;
#pragma unroll
    for (int i = 0; i < 8; ++i) {
        run += v[i];
        int idx = base + i;
        if (idx < m) pre[idx + 1] = run;
    }
    if (b == 0 && t == 0) pre[0] = 0;
}

// ---------------------------------------------------------------------------
// Layer-1 GEMM body (smem-pointer form for the heterogeneous kernel).
// ---------------------------------------------------------------------------
static __device__ __forceinline__ void gemm1_body(
    short* __restrict__ smem, const float* __restrict__ x,
    const unsigned short* __restrict__ Wt, unsigned short* __restrict__ Zl,
    unsigned short* __restrict__ Zr, int n, int bid) {
    constexpr int K = 128, LDA = K + 8, M = 128, MT = 8, KS = 4, QROW = 16;
    short* At = smem;             // 64 x LDA
    short* Bt = smem + 64 * LDA;  // 128 x LDA
    const int t = threadIdx.x;
    const int nodeBase = bid * 64;

    for (int q = t; q < 64 * QROW; q += 256) {
        int row = q / QROW;
        int k0 = (q % QROW) * 8;
        int node = nodeBase + row;
        short8 s = {0, 0, 0, 0, 0, 0, 0, 0};
        if (node < n) {
            const float* A = x + (size_t)node * K + k0;
            float4 v0 = *(const float4*)A;
            float4 v1 = *(const float4*)(A + 4);
            s[0] = f2bf(v0.x); s[1] = f2bf(v0.y);
            s[2] = f2bf(v0.z); s[3] = f2bf(v0.w);
            s[4] = f2bf(v1.x); s[5] = f2bf(v1.y);
            s[6] = f2bf(v1.z); s[7] = f2bf(v1.w);
        }
        *(short8*)&At[row * LDA + k0] = s;
    }
    for (int q = t; q < M * QROW; q += 256) {
        int row = q / QROW;
        int k0 = (q % QROW) * 8;
        *(short8*)&Bt[row * LDA + k0] =
            *(const short8*)((const short*)Wt + (size_t)row * K + k0);
    }
    __syncthreads();

    const int wave = t >> 6;
    const int lane = t & 63;
    const int m0 = wave * 16;
    const int fl = lane & 15;
    const int quad = lane >> 4;

    floatx4 acc[MT];
#pragma unroll
    for (int nt = 0; nt < MT; ++nt) acc[nt] = (floatx4){0.f, 0.f, 0.f, 0.f};

#pragma unroll
    for (int ks = 0; ks < KS; ++ks) {
        const int kb = ks * 32 + quad * 8;
        short8 a = *(const short8*)&At[(m0 + fl) * LDA + kb];
#pragma unroll
        for (int nt = 0; nt < MT; ++nt) {
            short8 b = *(const short8*)&Bt[(nt * 16 + fl) * LDA + kb];
            acc[nt] = __builtin_amdgcn_mfma_f32_16x16x32_bf16(a, b, acc[nt], 0, 0, 0);
        }
    }

#pragma unroll
    for (int nt = 0; nt < MT; ++nt) {
        const int col = nt * 16 + fl;
#pragma unroll
        for (int r = 0; r < 4; ++r) {
            int node = nodeBase + m0 + quad * 4 + r;
            if (node < n) {
                unsigned short v = (unsigned short)f2bf(acc[nt][r]);
                if (col < HID)
                    Zl[(size_t)node * HID + col] = v;
                else
                    Zr[(size_t)node * HID + (col - HID)] = v;
            }
        }
    }
}

// Heterogeneous launch: blocks [0,nbe) = bucket scatter (64-node buckets,
// packed (loc<<26)|src), rest = layer-1 GEMM tiles. No spin-waits: both
// halves depend only on already-completed dispatches.
__global__ __launch_bounds__(256) void scatter_gemm1(
    const int* __restrict__ ei, int ne, int n, const int* __restrict__ sbase,
    unsigned* __restrict__ ebuf, int nbe, const float* __restrict__ x,
    const unsigned short* __restrict__ wt1, unsigned short* __restrict__ zl,
    unsigned short* __restrict__ zr) {
    __shared__ __align__(16) short smem[(64 + 128) * 136];
    const int b = blockIdx.x;
    if (b < nbe) {
        int* bins = (int*)smem;
        const int t = threadIdx.x;
        const int nbuck = (n + 63) >> 6;
        for (int i = t; i < nbuck; i += 256) bins[i] = 0;
        __syncthreads();
        const int e0 = b * NE_BLK;
        const int lim = (e0 + NE_BLK < ne) ? (e0 + NE_BLK) : ne;
        for (int e = e0 + t; e < lim; e += 256) {
            int d = ei[ne + e];
            int s = ei[e];
            int bk = d >> 6;
            int r = atomicAdd(&bins[bk], 1);
            int p = sbase[(size_t)bk * nbe + b] + r;
            ebuf[p] = ((unsigned)(d & 63) << 26) | (unsigned)s;
        }
    } else {
        gemm1_body(smem, x, wt1, zl, zr, n, b - nbe);
    }
}

// ---------------------------------------------------------------------------
// Layer-1 aggregate, 64-node tile per block. In-LDS counting sort, then
// quarter-wave gather. Exports sorted edge list (csrO) + per-node degree
// (degO) for reuse by agg_gemm2. h = sigmoid(mean(Zl)+Zr+bias), bf16 out.
// ---------------------------------------------------------------------------
__global__ __launch_bounds__(256) void agg_h(
    const unsigned short* __restrict__ Zl, const unsigned short* __restrict__ Zr,
    const unsigned* __restrict__ ebuf, const int* __restrict__ sbase, int nbe,
    const float* __restrict__ bias, unsigned short* __restrict__ hout,
    int* __restrict__ csrO, int* __restrict__ degO, int n) {
    __shared__ int elist[ECAP];
    __shared__ int cnt[64];
    __shared__ int pos[64];
    const int t = threadIdx.x;
    const int tile = blockIdx.x;
    const int base = tile * 64;
    const int E0 = sbase[(size_t)tile * nbe];
    const int E1 = sbase[(size_t)(tile + 1) * nbe];
    const int nedge = E1 - E0;

    const int lane = t & 63, wave = t >> 6;
    const int sub = lane >> 4, col = lane & 15;

    float a[4][4];
    int totd[4];
#pragma unroll
    for (int p = 0; p < 4; ++p) {
        totd[p] = 0;
#pragma unroll
        for (int j = 0; j < 4; ++j) a[p][j] = 0.f;
    }

    for (int c0 = 0; c0 < nedge; c0 += ECAP) {
        const int cn = (nedge - c0 < ECAP) ? (nedge - c0) : ECAP;
        TILE_SORT()
        // export sorted srcs for reuse by agg_gemm2
        for (int j = t; j < cn; j += 256) csrO[E0 + c0 + j] = elist[j];
#pragma unroll
        for (int p = 0; p < 4; ++p) {
            const int i = wave * 16 + p * 4 + sub;
            const int s = pos[i] - cnt[i];
            const int d = cnt[i];
            totd[p] += d;
            float* AC = a[p];
            GATHER4(elist, Zl, AC)
        }
    }

#pragma unroll
    for (int p = 0; p < 4; ++p) {
        const int i = wave * 16 + p * 4 + sub;
        const int node = base + i;
        if (node < n) {
            if (col == 0) degO[node] = totd[p];
            float inv = 1.0f / fmaxf((float)totd[p], 1.0f);
            uint2 z = *(const uint2*)(Zr + (size_t)node * 64 + col * 4);
            float4 bb = ((const float4*)bias)[col];
            float r0 = a[p][0] * inv + bf2f((unsigned short)(z.x & 0xffffu)) + bb.x;
            float r1 = a[p][1] * inv + bf2f((unsigned short)(z.x >> 16)) + bb.y;
            float r2 = a[p][2] * inv + bf2f((unsigned short)(z.y & 0xffffu)) + bb.z;
            float r3 = a[p][3] * inv + bf2f((unsigned short)(z.y >> 16)) + bb.w;
            r0 = 1.0f / (1.0f + __expf(-r0));
            r1 = 1.0f / (1.0f + __expf(-r1));
            r2 = 1.0f / (1.0f + __expf(-r2));
            r3 = 1.0f / (1.0f + __expf(-r3));
            uint2 pk;
            pk.x = (unsigned)(unsigned short)f2bf(r0) |
                   ((unsigned)(unsigned short)f2bf(r1) << 16);
            pk.y = (unsigned)(unsigned short)f2bf(r2) |
                   ((unsigned)(unsigned short)f2bf(r3) << 16);
            *(uint2*)(hout + (size_t)node * 64 + col * 4) = pk;
        }
    }
}

// ---------------------------------------------------------------------------
// Fused layer-2: fast path reuses agg_h's sorted list (coalesced csr load +
// 64-wide shfl prefix of deg — no sort); fallback sorts for tiles > ECAP.
// gather-mean(h) -> bf16 A-tile left half; h right half; K=128 cat-GEMM.
// ---------------------------------------------------------------------------
__global__ __launch_bounds__(256) void agg_gemm2(
    const unsigned short* __restrict__ h, const unsigned short* __restrict__ Wt,
    const float* __restrict__ bias, const unsigned* __restrict__ ebuf,
    const int* __restrict__ sbase, int nbe, const int* __restrict__ csrI,
    const int* __restrict__ degI, float* __restrict__ out, int n) {
    constexpr int LDA = 136;
    __shared__ __align__(16) short At[64 * LDA];
    __shared__ __align__(16) short Bt[48 * LDA];
    __shared__ int elist[ECAP];
    __shared__ int cnt[64];
    __shared__ int pos[64];
    const int t = threadIdx.x;
    const int tile = blockIdx.x;
    const int base = tile * 64;
    const int E0 = sbase[(size_t)tile * nbe];
    const int E1 = sbase[(size_t)(tile + 1) * nbe];
    const int nedge = E1 - E0;

    // stage h rows into At[:, 64:128)
    for (int q = t; q < 64 * 8; q += 256) {
        int row = q >> 3, k0 = (q & 7) * 8;
        int node = base + row;
        short8 s = {0, 0, 0, 0, 0, 0, 0, 0};
        if (node < n) s = *(const short8*)(h + (size_t)node * 64 + k0);
        *(short8*)&At[row * LDA + 64 + k0] = s;
    }
    // stage Bt (48 x 128)
    for (int q = t; q < 48 * 16; q += 256) {
        int row = q >> 4, k0 = (q & 15) * 8;
        *(short8*)&Bt[row * LDA + k0] =
            *(const short8*)((const short*)Wt + (size_t)row * 128 + k0);
    }

    const int lane = t & 63, wave = t >> 6;
    const int sub = lane >> 4, col = lane & 15;

    float a[4][4];
    int totd[4];
#pragma unroll
    for (int p = 0; p < 4; ++p) {
        totd[p] = 0;
#pragma unroll
        for (int j = 0; j < 4; ++j) a[p][j] = 0.f;
    }

    if (nedge <= ECAP) {
        // fast path: reuse sorted list from agg_h
        for (int j = t; j < nedge; j += 256) elist[j] = csrI[E0 + j];
        if (t < 64) {
            int node = base + t;
            int v = (node < n) ? degI[node] : 0;
            cnt[t] = v;
            int xx = v;
#pragma unroll
            for (int o = 1; o < 64; o <<= 1) {
                int y = __shfl_up(xx, o);
                if (t >= o) xx += y;
            }
            pos[t] = xx;  // inclusive end
        }
        __syncthreads();
#pragma unroll
        for (int p = 0; p < 4; ++p) {
            const int i = wave * 16 + p * 4 + sub;
            const int s = pos[i] - cnt[i];
            const int d = cnt[i];
            totd[p] = d;
            float* AC = a[p];
            GATHER4(elist, h, AC)
        }
    } else {
        // fallback: sort in-tile (chunked)
        for (int c0 = 0; c0 < nedge; c0 += ECAP) {
            const int cn = (nedge - c0 < ECAP) ? (nedge - c0) : ECAP;
            TILE_SORT()
#pragma unroll
            for (int p = 0; p < 4; ++p) {
                const int i = wave * 16 + p * 4 + sub;
                const int s = pos[i] - cnt[i];
                const int d = cnt[i];
                totd[p] += d;
                float* AC = a[p];
                GATHER4(elist, h, AC)
            }
        }
    }

    // gather epilogue -> At left half (bf16 mean; zero rows for node>=n)
#pragma unroll
    for (int p = 0; p < 4; ++p) {
        const int i = wave * 16 + p * 4 + sub;
        float inv = 1.0f / fmaxf((float)totd[p], 1.0f);
        uint2 pk;
        pk.x = (unsigned)(unsigned short)f2bf(a[p][0] * inv) |
               ((unsigned)(unsigned short)f2bf(a[p][1] * inv) << 16);
        pk.y = (unsigned)(unsigned short)f2bf(a[p][2] * inv) |
               ((unsigned)(unsigned short)f2bf(a[p][3] * inv) << 16);
        *(uint2*)&At[i * LDA + col * 4] = pk;
    }
    __syncthreads();

    // MFMA: K=128, 3 col-tiles (48 cols, 40 valid)
    const int m0 = wave * 16;
    const int fl = lane & 15;
    const int quad = lane >> 4;
    floatx4 acc[3];
#pragma unroll
    for (int nt = 0; nt < 3; ++nt) acc[nt] = (floatx4){0.f, 0.f, 0.f, 0.f};
#pragma unroll
    for (int ks = 0; ks < 4; ++ks) {
        const int kb = ks * 32 + quad * 8;
        short8 av = *(const short8*)&At[(m0 + fl) * LDA + kb];
#pragma unroll
        for (int nt = 0; nt < 3; ++nt) {
            short8 bv = *(const short8*)&Bt[(nt * 16 + fl) * LDA + kb];
            acc[nt] = __builtin_amdgcn_mfma_f32_16x16x32_bf16(av, bv, acc[nt], 0, 0, 0);
        }
    }
#pragma unroll
    for (int nt = 0; nt < 3; ++nt) {
        const int col2 = nt * 16 + fl;
        if (col2 < NCLS) {
            float bv = bias[col2];
#pragma unroll
            for (int r = 0; r < 4; ++r) {
                int node = base + m0 + quad * 4 + r;
                if (node < n)
                    out[(size_t)node * NCLS + col2] = acc[nt][r] + bv;
            }
        }
    }
}

// ---------------------------------------------------------------------------
extern "C" void kernel_launch(void* const* d_in, const int* in_sizes, int n_in,
                              void* d_out, int out_size, void* d_ws,
                              size_t ws_size, hipStream_t stream) {
    const float* x = (const float*)d_in[0];
    const int* ei = (const int*)d_in[1];
    const float* W1l = (const float*)d_in[2];
    const float* b1 = (const float*)d_in[3];
    const float* W1r = (const float*)d_in[4];
    const float* W2l = (const float*)d_in[5];
    const float* b2 = (const float*)d_in[6];
    const float* W2r = (const float*)d_in[7];
    float* out = (float*)d_out;

    const int n = in_sizes[0] / N_FEAT;  // 100000
    const int ne = in_sizes[1] / 2;      // 600000

    const int nbe = (ne + NE_BLK - 1) / NE_BLK;   // 147 edge blocks
    const int nbuck = (n + 63) >> 6;              // 1563 tiles
    const int tot = nbuck * nbe;                  // ~230K

    // ws layout
    unsigned short* zl1 = (unsigned short*)d_ws;
    unsigned short* zr1 = zl1 + (size_t)n * HID;
    unsigned short* h = zr1 + (size_t)n * HID;
    unsigned short* wt1 = h + (size_t)n * HID;
    unsigned short* wt2 = wt1 + 128 * 128;
    unsigned* ebuf = (unsigned*)(wt2 + 48 * 128);
    int* csr = (int*)(ebuf + ne);
    int* deg = csr + ne;
    int* bh = deg + n;
    int* sbase = bh + tot;
    int* bsums = sbase + (tot + 1);
    int* flags = bsums + 256;

    const int gblocks = (n + 63) / 64;            // 1563
    const int nsb = (tot + 2047) / 2048;          // 113 scan blocks

    // 1) weight prep + 64-node-bucket histogram + flag zero
    prep_hist<<<nbe, 256, 0, stream>>>(W1l, W1r, W2l, W2r, wt1, wt2, flags,
                                       ei, ne, n, bh, nbe);
    // 2) count-matrix scan -> per-(bucket,block) bases
    scan_fused<<<nsb, 256, 0, stream>>>(bh, sbase, tot, bsums, flags);
    // 3) bucket scatter + layer-1 GEMM (independent, heterogeneous blocks)
    scatter_gemm1<<<nbe + gblocks, 256, 0, stream>>>(ei, ne, n, sbase, ebuf,
                                                     nbe, x, wt1, zl1, zr1);
    // 4) layer-1 aggregate -> h (+ export sorted csr/deg)
    agg_h<<<gblocks, 256, 0, stream>>>(zl1, zr1, ebuf, sbase, nbe, b1, h, csr,
                                       deg, n);
    // 5) fused layer-2 gather + cat-GEMM -> out (reuses sorted csr/deg)
    agg_gemm2<<<gblocks, 256, 0, stream>>>(h, wt2, b2, ebuf, sbase, nbe, csr,
                                           deg, out, n);
}